// Round 6
// baseline (250.856 us; speedup 1.0000x reference)
//
#include <hip/hip_runtime.h>

// PyramidROIAlign: out[b,n,py,px,c] = bilinear crop from the FPN level
// selected per-box by log2(sqrt(h*w)*sqrt(area)/224).
//
// v5 = v4b with one wave per TWO pool cells (grid B*N*25, was B*N*49).
// Post-mortem history: v2 (serial 12-cell loop) regressed -> keep full
// unroll; v4b (XCD swizzle + NT stores) was null -> reads are L3-resident,
// BW levers exhausted. Remaining theory: per-wave overhead/issue bound
// (~60 VALU setup per cell, one tiny work unit per wave). v5 amortizes
// setup 2x and doubles VMEM ILP (8 corner loads in flight, no loop).
// Lane t handles channels [4t,4t+4) via float4; cell 48 pairs with nothing
// (wave k=24 does one cell, wave-uniform branch).
// (Round 5 bench was an infra failure -- container acquisition -- resubmit.)

typedef float floatx4 __attribute__((ext_vector_type(4)));

__global__ __launch_bounds__(64) void roi_align_kernel(
    const float* __restrict__ boxes,   // (B,N,4) y1,x1,y2,x2
    const float* __restrict__ meta,    // (B,14); meta[4],meta[5] = img H,W
    const float* __restrict__ f2,      // (B,256,256,256)
    const float* __restrict__ f3,      // (B,128,128,256)
    const float* __restrict__ f4,      // (B, 64, 64,256)
    const float* __restrict__ f5,      // (B, 32, 32,256)
    float* __restrict__ out,           // (B,N,7,7,256)
    int N)
{
    const int C = 256;

    // ---- bijective XCD swizzle (m204) ----
    int orig = blockIdx.x;
    int nwg  = gridDim.x;
    int q = nwg >> 3, r = nwg & 7;
    int xcd  = orig & 7;
    int bid  = (xcd < r ? xcd * (q + 1) : r * (q + 1) + (xcd - r) * q)
             + (orig >> 3);

    int bn = bid / 25;                  // box index: b*N + n
    int k  = bid - bn * 25;             // cell-pair index 0..24
    int c0 = 2 * k;                     // first cell 0..48
    bool has2 = (c0 + 1 < 49);          // wave-uniform
    int b  = bn / N;
    int lane = threadIdx.x;             // 0..63 -> 4 channels each

    // ---- per-box scalar setup (wave-uniform, amortized over 2 cells) ----
    float y1 = boxes[bn * 4 + 0];
    float x1 = boxes[bn * 4 + 1];
    float y2 = boxes[bn * 4 + 2];
    float x2 = boxes[bn * 4 + 3];
    float h = y2 - y1;
    float w = x2 - x1;

    // roi_level = clip(4 + round(log2(sqrt(h*w) / (224/sqrt(imgH*imgW)))), 2, 5)
    float area = meta[4] * meta[5];
    float lvl  = log2f(sqrtf(h * w) / (224.0f / sqrtf(area)));
    float rl   = 4.0f + rintf(lvl);          // rintf = half-to-even, matches jnp.round
    rl = fminf(fmaxf(rl, 2.0f), 5.0f);       // -inf (degenerate box) clamps to 2
    int level = (int)rl;

    const float* fm;
    int H;
    if (level == 2)      { fm = f2; H = 256; }
    else if (level == 3) { fm = f3; H = 128; }
    else if (level == 4) { fm = f4; H = 64;  }
    else                 { fm = f5; H = 32;  }
    int W = H;

    float sy = (h * (float)(H - 1)) / 6.0f;
    float sx = (w * (float)(W - 1)) / 6.0f;
    float ybase = y1 * (float)(H - 1);
    float xbase = x1 * (float)(W - 1);

    const float* fb = fm + (size_t)b * H * W * C;

    // ---- cell A coords ----
    int pyA = c0 / 7, pxA = c0 - pyA * 7;
    float ysA = ybase + (float)pyA * sy;
    float xsA = xbase + (float)pxA * sx;
    float y0fA = floorf(ysA), x0fA = floorf(xsA);
    int y0A = min(max((int)y0fA, 0), H - 1);
    int yiA = min(y0A + 1, H - 1);
    int x0A = min(max((int)x0fA, 0), H - 1);
    int xiA = min(x0A + 1, H - 1);
    float fyA = ysA - y0fA, fxA = xsA - x0fA;

    // ---- cell B coords ----
    int c1 = has2 ? c0 + 1 : c0;        // degenerate: recompute cell A (masked store)
    int pyB = c1 / 7, pxB = c1 - pyB * 7;
    float ysB = ybase + (float)pyB * sy;
    float xsB = xbase + (float)pxB * sx;
    float y0fB = floorf(ysB), x0fB = floorf(xsB);
    int y0B = min(max((int)y0fB, 0), H - 1);
    int yiB = min(y0B + 1, H - 1);
    int x0B = min(max((int)x0fB, 0), H - 1);
    int xiB = min(x0B + 1, H - 1);
    float fyB = ysB - y0fB, fxB = xsB - x0fB;

    // ---- issue all 8 corner loads (independent, in flight together) ----
    const float4* ptlA = (const float4*)(fb + ((size_t)y0A * W + x0A) * C);
    const float4* ptrA = (const float4*)(fb + ((size_t)y0A * W + xiA) * C);
    const float4* pblA = (const float4*)(fb + ((size_t)yiA * W + x0A) * C);
    const float4* pbrA = (const float4*)(fb + ((size_t)yiA * W + xiA) * C);
    const float4* ptlB = (const float4*)(fb + ((size_t)y0B * W + x0B) * C);
    const float4* ptrB = (const float4*)(fb + ((size_t)y0B * W + xiB) * C);
    const float4* pblB = (const float4*)(fb + ((size_t)yiB * W + x0B) * C);
    const float4* pbrB = (const float4*)(fb + ((size_t)yiB * W + xiB) * C);

    float4 tlA = ptlA[lane];
    float4 trA = ptrA[lane];
    float4 blA = pblA[lane];
    float4 brA = pbrA[lane];
    float4 tlB = ptlB[lane];
    float4 trB = ptrB[lane];
    float4 blB = pblB[lane];
    float4 brB = pbrB[lane];

    floatx4 oA, oB;
    {
        float top, bot;
        top = tlA.x + (trA.x - tlA.x) * fxA; bot = blA.x + (brA.x - blA.x) * fxA;
        oA.x = top + (bot - top) * fyA;
        top = tlA.y + (trA.y - tlA.y) * fxA; bot = blA.y + (brA.y - blA.y) * fxA;
        oA.y = top + (bot - top) * fyA;
        top = tlA.z + (trA.z - tlA.z) * fxA; bot = blA.z + (brA.z - blA.z) * fxA;
        oA.z = top + (bot - top) * fyA;
        top = tlA.w + (trA.w - tlA.w) * fxA; bot = blA.w + (brA.w - blA.w) * fxA;
        oA.w = top + (bot - top) * fyA;
    }
    {
        float top, bot;
        top = tlB.x + (trB.x - tlB.x) * fxB; bot = blB.x + (brB.x - blB.x) * fxB;
        oB.x = top + (bot - top) * fyB;
        top = tlB.y + (trB.y - tlB.y) * fxB; bot = blB.y + (brB.y - blB.y) * fxB;
        oB.y = top + (bot - top) * fyB;
        top = tlB.z + (trB.z - tlB.z) * fxB; bot = blB.z + (brB.z - blB.z) * fxB;
        oB.z = top + (bot - top) * fyB;
        top = tlB.w + (trB.w - tlB.w) * fxB; bot = blB.w + (brB.w - blB.w) * fxB;
        oB.w = top + (bot - top) * fyB;
    }

    float* ob = out + (size_t)bn * 49 * C;
    __builtin_nontemporal_store(oA, (floatx4*)(ob + (size_t)c0 * C) + lane);
    if (has2)
        __builtin_nontemporal_store(oB, (floatx4*)(ob + (size_t)(c0 + 1) * C) + lane);
}

extern "C" void kernel_launch(void* const* d_in, const int* in_sizes, int n_in,
                              void* d_out, int out_size, void* d_ws, size_t ws_size,
                              hipStream_t stream) {
    const float* boxes = (const float*)d_in[0];
    const float* meta  = (const float*)d_in[1];
    const float* f2    = (const float*)d_in[2];
    const float* f3    = (const float*)d_in[3];
    const float* f4    = (const float*)d_in[4];
    const float* f5    = (const float*)d_in[5];
    float* out = (float*)d_out;

    int B = in_sizes[1] / 14;            // image_meta is (B,14)
    int N = in_sizes[0] / (4 * B);       // boxes is (B,N,4)

    int grid = B * N * 25;               // one wave per 2 pool cells
    roi_align_kernel<<<grid, 64, 0, stream>>>(boxes, meta, f2, f3, f4, f5, out, N);
}

// Round 7
// 241.947 us; speedup vs baseline: 1.0368x; 1.0368x over previous
//
#include <hip/hip_runtime.h>

// PyramidROIAlign: out[b,n,py,px,c] = bilinear crop from the FPN level
// selected per-box by log2(sqrt(h*w)*sqrt(area)/224).
//
// v6 = v3 verbatim (the empirically best variant, 245.5 us). Session
// post-mortem: three orthogonal lever families all probed null or negative
// against v3 --
//   v2  4-wave/box serial loop      -> -12 us (TLP loss dominates locality)
//   v4b XCD swizzle + NT stores     -> null (reads L3/L2-resident; write
//                                      stream not the constraint)
//   v5  2 cells/wave, 8-load ILP    -> +5 us (register context growth,
//                                      no issue-bound win)
// Total dur_us is dominated by ~163 us of harness poison fills (2x512 MiB
// at 82-83% HBM peak, which also flush L3 every iteration); the kernel
// itself sits below the 80 us top-5 cutoff, near its compulsory-traffic
// floor (100 MB output writes + cold scattered corner reads).
//
// Structure: one 448-thread block (7 waves) per (box, pool-row). Wave px
// handles cell (py,px); lane t handles channels [4t,4t+4) via float4.
// Full TLP (98k waves, no per-wave loop), row-sharing cells on one CU.

__global__ __launch_bounds__(448) void roi_align_kernel(
    const float* __restrict__ boxes,   // (B,N,4) y1,x1,y2,x2
    const float* __restrict__ meta,    // (B,14); meta[4],meta[5] = img H,W
    const float* __restrict__ f2,      // (B,256,256,256)
    const float* __restrict__ f3,      // (B,128,128,256)
    const float* __restrict__ f4,      // (B, 64, 64,256)
    const float* __restrict__ f5,      // (B, 32, 32,256)
    float* __restrict__ out,           // (B,N,7,7,256)
    int N)
{
    const int C = 256;
    int bid = blockIdx.x;               // bn*7 + py
    int bn  = bid / 7;
    int py  = bid - bn * 7;
    int b   = bn / N;
    int px  = threadIdx.x >> 6;         // wave id 0..6 = pool column
    int lane = threadIdx.x & 63;        // 4 channels each

    // ---- per-box scalar setup (wave-uniform) ----
    float y1 = boxes[bn * 4 + 0];
    float x1 = boxes[bn * 4 + 1];
    float y2 = boxes[bn * 4 + 2];
    float x2 = boxes[bn * 4 + 3];
    float h = y2 - y1;
    float w = x2 - x1;

    // roi_level = clip(4 + round(log2(sqrt(h*w) / (224/sqrt(imgH*imgW)))), 2, 5)
    float area = meta[4] * meta[5];
    float lvl  = log2f(sqrtf(h * w) / (224.0f / sqrtf(area)));
    float rl   = 4.0f + rintf(lvl);          // rintf = half-to-even, matches jnp.round
    rl = fminf(fmaxf(rl, 2.0f), 5.0f);       // -inf (degenerate box) clamps to 2
    int level = (int)rl;

    const float* fm;
    int H;
    if (level == 2)      { fm = f2; H = 256; }
    else if (level == 3) { fm = f3; H = 128; }
    else if (level == 4) { fm = f4; H = 64;  }
    else                 { fm = f5; H = 32;  }
    int W = H;

    // ---- sample coordinates (match reference fp32 op order) ----
    float sy = (h * (float)(H - 1)) / 6.0f;
    float sx = (w * (float)(W - 1)) / 6.0f;
    float ys = y1 * (float)(H - 1) + (float)py * sy;
    float xs = x1 * (float)(W - 1) + (float)px * sx;
    float y0f = floorf(ys);
    float x0f = floorf(xs);
    int y0 = min(max((int)y0f, 0), H - 1);
    int yi = min(y0 + 1, H - 1);
    int x0 = min(max((int)x0f, 0), H - 1);
    int xi = min(x0 + 1, H - 1);
    float fy = ys - y0f;
    float fx = xs - x0f;

    size_t base = (size_t)b * H * W * C;
    const float4* ptl = (const float4*)(fm + base + ((size_t)y0 * W + x0) * C);
    const float4* ptr = (const float4*)(fm + base + ((size_t)y0 * W + xi) * C);
    const float4* pbl = (const float4*)(fm + base + ((size_t)yi * W + x0) * C);
    const float4* pbr = (const float4*)(fm + base + ((size_t)yi * W + xi) * C);

    float4 tl = ptl[lane];
    float4 tr = ptr[lane];
    float4 bl = pbl[lane];
    float4 br = pbr[lane];

    float4 o;
    {
        float top = tl.x + (tr.x - tl.x) * fx;
        float bot = bl.x + (br.x - bl.x) * fx;
        o.x = top + (bot - top) * fy;
    }
    {
        float top = tl.y + (tr.y - tl.y) * fx;
        float bot = bl.y + (br.y - bl.y) * fx;
        o.y = top + (bot - top) * fy;
    }
    {
        float top = tl.z + (tr.z - tl.z) * fx;
        float bot = bl.z + (br.z - bl.z) * fx;
        o.z = top + (bot - top) * fy;
    }
    {
        float top = tl.w + (tr.w - tl.w) * fx;
        float bot = bl.w + (br.w - bl.w) * fx;
        o.w = top + (bot - top) * fy;
    }

    float4* po = (float4*)(out + ((size_t)bn * 49 + (size_t)py * 7 + px) * C);
    po[lane] = o;
}

extern "C" void kernel_launch(void* const* d_in, const int* in_sizes, int n_in,
                              void* d_out, int out_size, void* d_ws, size_t ws_size,
                              hipStream_t stream) {
    const float* boxes = (const float*)d_in[0];
    const float* meta  = (const float*)d_in[1];
    const float* f2    = (const float*)d_in[2];
    const float* f3    = (const float*)d_in[3];
    const float* f4    = (const float*)d_in[4];
    const float* f5    = (const float*)d_in[5];
    float* out = (float*)d_out;

    int B = in_sizes[1] / 14;            // image_meta is (B,14)
    int N = in_sizes[0] / (4 * B);       // boxes is (B,N,4)

    int grid = B * N * 7;                // one 7-wave block per (box, pool row)
    roi_align_kernel<<<grid, 448, 0, stream>>>(boxes, meta, f2, f3, f4, f5, out, N);
}